// Round 1
// baseline (2017.993 us; speedup 1.0000x reference)
//
#include <hip/hip_runtime.h>
#include <math.h>

// Problem dims (fixed by reference)
#define SEQ    128
#define BATCH  64
#define HD     1024
#define NG     4096
#define TOUT   32
#define NE     65536      // BATCH*HD
#define NHBUF  160        // SEQ + TOUT h buffers (write-once rotation)
#define NBAR   1024       // barrier words (4 counters, 256B apart)

typedef __attribute__((ext_vector_type(8))) short    short8;
typedef __attribute__((ext_vector_type(4))) float    f32x4;

#define MFMA16(a,b,c) __builtin_amdgcn_mfma_f32_16x16x32_bf16((a),(b),(c),0,0,0)

__device__ __forceinline__ ushort bf16_rne(float x) {
    union { float f; unsigned u; } v; v.f = x;
    unsigned r = v.u + 0x7FFF + ((v.u >> 16) & 1);
    return (ushort)(r >> 16);
}

// device-coherent (agent-scope) store: push to coherence point, no fences
__device__ __forceinline__ void cstore32(void* p, unsigned v) {
    __hip_atomic_store((unsigned*)p, v, __ATOMIC_RELAXED, __HIP_MEMORY_SCOPE_AGENT);
}

// ---------------------------------------------------------------------------
// fp32 -> bf16 (RNE), 4 elems/thread; n % 1024 == 0
// ---------------------------------------------------------------------------
__global__ __launch_bounds__(256) void cvt_bf16(
    const float* __restrict__ src, ushort* __restrict__ dst, int n)
{
    int i = (blockIdx.x * 256 + threadIdx.x) * 4;
    if (i < n) {
        float4 v = *(const float4*)(src + i);
        ushort4 o;
        o.x = bf16_rne(v.x); o.y = bf16_rne(v.y);
        o.z = bf16_rne(v.z); o.w = bf16_rne(v.w);
        *(ushort4*)(dst + i) = o;
    }
}

// prep: h0 -> bf16 into hbuf(0); zero barrier counters.
__global__ __launch_bounds__(256) void prep(
    const float* __restrict__ h0, ushort* __restrict__ h0b,
    unsigned* __restrict__ bar)
{
    int i = blockIdx.x * 256 + threadIdx.x;
    h0b[i] = bf16_rne(h0[i]);
    if (blockIdx.x == 0)
        for (int k = threadIdx.x; k < NBAR; k += 256) bar[k] = 0u;
}

// ---------------------------------------------------------------------------
// Flat monotonic group barrier (64 blocks/group).
// arrive: drain stores, block-sync, one fetch_add on the group counter.
// wait:   thread 0 polls counter >= 64*epoch (monotonic, never reset in-launch).
// Chain after last arrival: 1 atomic RT + poll detect (~2 L3 RTs) vs the old
// sub->root->release->poll (~4 RTs).
// ---------------------------------------------------------------------------
__device__ __forceinline__ void g_arrive(unsigned* ctr) {
    asm volatile("s_waitcnt vmcnt(0) lgkmcnt(0)" ::: "memory");
    __syncthreads();
    if (threadIdx.x == 0)
        __hip_atomic_fetch_add(ctr, 1u, __ATOMIC_RELAXED, __HIP_MEMORY_SCOPE_AGENT);
}
__device__ __forceinline__ void g_wait(unsigned* ctr, unsigned tgt) {
    if (threadIdx.x == 0) {
        while (__hip_atomic_load(ctr, __ATOMIC_RELAXED, __HIP_MEMORY_SCOPE_AGENT) < tgt)
            __builtin_amdgcn_s_sleep(1);
    }
    __syncthreads();
}

// ---------------------------------------------------------------------------
// Stage 16x1024 bf16 tile via NORMAL cached loads (write-once buffers make
// this safe); 8 loads batched in regs then 8 LDS stores (pitch 1032).
// ---------------------------------------------------------------------------
__device__ __forceinline__ void stageN(const ushort* __restrict__ src,
                                       ushort* __restrict__ dst)
{
    const int tid = threadIdx.x;
    short8 t[8];
    #pragma unroll
    for (int i = 0; i < 8; i++) {
        int idx = i * 256 + tid;
        t[i] = *(const short8*)(src + ((size_t)(idx >> 7) << 10) + (idx & 127) * 8);
    }
    #pragma unroll
    for (int i = 0; i < 8; i++) {
        int idx = i * 256 + tid;
        *(short8*)&dst[(idx >> 7) * 1032 + (idx & 127) * 8] = t[i];
    }
}

// ---------------------------------------------------------------------------
// Single persistent cooperative LSTM kernel (all 128 encode + 32 decode steps).
// Block (bg=blk>>6, ug=blk&63): cell = 16-batch x 16-unit tile (wave = gate);
// proj = 16x16 y patch (wave split-K). x-GEMM folded into the cell (computed
// in the barrier-wait shadow); log-softmax folded into the next cell (every
// block redundantly computes lse for its 16 rows -> uniform control flow,
// 2 barriers/decode step instead of 3 + softmax phase).
// Epoch schedule: 128 (encode) + 1 (proj0) + 62 (31 x cell+proj) = 191
// arrivals per block, identical order on all blocks of a group.
// ---------------------------------------------------------------------------
__global__ __launch_bounds__(256, 1) void lstm_coop(
    const ushort* __restrict__ Wih, const ushort* __restrict__ Whh,
    const ushort* __restrict__ Wout, const ushort* __restrict__ Xbf,
    ushort* __restrict__ Hbase, float* __restrict__ Ybase,
    unsigned* __restrict__ bar,
    const float* __restrict__ b_ih, const float* __restrict__ b_hh,
    const float* __restrict__ b_out, const float* __restrict__ c0,
    float* __restrict__ out)
{
    __shared__ ushort xs[16 * 1032];   // x tile (encode: staged; decode: bf16(y-lse))
    __shared__ ushort hs[16 * 1032];   // h tile (persists proj -> next cell)
    __shared__ float  gbuf[1088];

    const int blk  = blockIdx.x;
    const int bg   = blk >> 6, ug = blk & 63;
    const int tid  = threadIdx.x;
    const int wave = tid >> 6, lane = tid & 63;
    const int l15  = lane & 15, q8 = (lane >> 4) * 8, r0 = (lane >> 4) * 4;
    const int b    = tid >> 4, u = tid & 15;

    unsigned* ctr = bar + bg * 64;     // 256B apart per group
    unsigned ep = 0;

    const int gi = ug * 16 + u;
    const float bs0 = b_ih[gi]        + b_hh[gi];
    const float bs1 = b_ih[1024 + gi] + b_hh[1024 + gi];
    const float bs2 = b_ih[2048 + gi] + b_hh[2048 + gi];
    const float bs3 = b_ih[3072 + gi] + b_hh[3072 + gi];
    const int cidx = ((bg * 16 + b) << 10) + gi;
    float c_reg = c0[cidx];

    const ushort* wip = Wih + (((size_t)(wave * 1024 + ug * 16 + l15)) << 10) + q8;
    const ushort* whp = Whh + (((size_t)(wave * 1024 + ug * 16 + l15)) << 10) + q8;
    const ushort* wop = Wout + (((size_t)(ug * 16 + l15)) << 10) + wave * 256 + q8;
    const ushort* f0 = xs + l15 * 1032 + q8;
    const ushort* f1 = hs + l15 * 1032 + q8;

    auto hbuf = [&](int t) -> ushort* {
        return Hbase + (size_t)(NHBUF - 1 - t) * NE;
    };

    auto gwrite = [&](f32x4 acc) {
        #pragma unroll
        for (int r = 0; r < 4; r++)
            gbuf[(r0 + r) * 68 + wave * 16 + l15] = acc[r];
    };

    auto pointwise = [&](ushort* hnxt, bool fin) {
        float ig = gbuf[b * 68 + u]      + bs0;
        float fg = gbuf[b * 68 + 16 + u] + bs1;
        float gg = gbuf[b * 68 + 32 + u] + bs2;
        float og = gbuf[b * 68 + 48 + u] + bs3;
        float si = 1.f / (1.f + expf(-ig));
        float sf = 1.f / (1.f + expf(-fg));
        float so = 1.f / (1.f + expf(-og));
        float tg = tanhf(gg);
        float cn = sf * c_reg + si * tg;
        c_reg = cn;
        float hn = so * tanhf(cn);
        ushort hb16 = bf16_rne(hn);
        unsigned hi = (unsigned)(ushort)__shfl_down((int)hb16, 1);
        if ((u & 1) == 0)
            cstore32((void*)(hnxt + cidx), (unsigned)hb16 | (hi << 16));
        if (fin) {
            out[(size_t)TOUT * NE + cidx]       = hn;
            out[(size_t)(TOUT + 1) * NE + cidx] = cn;
        }
    };

    auto proj_step = [&](const ushort* hcur, float* ydst) {
        stageN(hcur + ((size_t)(bg * 16) << 10), hs);
        __syncthreads();
        const ushort* hpp = hs + l15 * 1032 + wave * 256 + q8;
        f32x4 ac = {0.f, 0.f, 0.f, 0.f};
        #pragma unroll
        for (int kk = 0; kk < 256; kk += 32)
            ac = MFMA16(*(const short8*)(hpp + kk), *(const short8*)(wop + kk), ac);
        #pragma unroll
        for (int r = 0; r < 4; r++)
            gbuf[wave * 256 + (r0 + r) * 16 + l15] = ac[r];
        __syncthreads();
        float vv = gbuf[b * 16 + u] + gbuf[256 + b * 16 + u]
                 + gbuf[512 + b * 16 + u] + gbuf[768 + b * 16 + u]
                 + b_out[ug * 16 + u];
        union { float f; unsigned uu; } cv; cv.f = vv;
        cstore32(ydst + (size_t)(bg * 16 + b) * 1024 + ug * 16 + u, cv.uu);
    };

    // Distributed log-softmax: every block loads its 16 y rows (64 f32/thread),
    // reduces lse per row within 16 contiguous lanes, writes its 16x16 out
    // patch, and (optionally) fills xs with bf16(y - lse) for the next cell.
    auto softlse = [&](const float* yb, float* outp, bool fill_xs) {
        const float* yrow = yb + (size_t)(bg * 16 + b) * 1024;
        float4 v[16];
        #pragma unroll
        for (int s = 0; s < 16; s++)
            v[s] = *(const float4*)(yrow + s * 64 + u * 4);
        float mx = -3.4e38f;
        #pragma unroll
        for (int s = 0; s < 16; s++)
            mx = fmaxf(mx, fmaxf(fmaxf(v[s].x, v[s].y), fmaxf(v[s].z, v[s].w)));
        #pragma unroll
        for (int k = 1; k < 16; k <<= 1)
            mx = fmaxf(mx, __shfl_xor(mx, k, 16));
        float sm = 0.f;
        #pragma unroll
        for (int s = 0; s < 16; s++)
            sm += expf(v[s].x - mx) + expf(v[s].y - mx)
                + expf(v[s].z - mx) + expf(v[s].w - mx);
        #pragma unroll
        for (int k = 1; k < 16; k <<= 1)
            sm += __shfl_xor(sm, k, 16);
        const float lse = mx + logf(sm);
        if ((u >> 2) == (ug & 3)) {        // this block writes cols ug*16..+16
            float4 o = v[ug >> 2];
            o.x -= lse; o.y -= lse; o.z -= lse; o.w -= lse;
            *(float4*)(outp + (size_t)(bg * 16 + b) * 1024 + ug * 16 + (u & 3) * 4) = o;
        }
        if (fill_xs) {
            ushort* xrow = &xs[b * 1032];
            #pragma unroll
            for (int s = 0; s < 16; s++) {
                ushort4 w4;
                w4.x = bf16_rne(v[s].x - lse); w4.y = bf16_rne(v[s].y - lse);
                w4.z = bf16_rne(v[s].z - lse); w4.w = bf16_rne(v[s].w - lse);
                *(ushort4*)(xrow + u * 4 + s * 64) = w4;
            }
        }
    };

    // ================= encode: 128 steps, 1 barrier each =================
    for (int t = 0; t < SEQ; t++) {
        // x tile + x-GEMM run in the barrier shadow (independent of h(t))
        stageN(Xbf + (size_t)t * NE + ((size_t)(bg * 16) << 10), xs);
        __syncthreads();
        f32x4 a0 = {0.f,0.f,0.f,0.f}, a1 = {0.f,0.f,0.f,0.f};
        #pragma unroll 8
        for (int kk = 0; kk < 512; kk += 32)
            a0 = MFMA16(*(const short8*)(f0 + kk), *(const short8*)(wip + kk), a0);
        #pragma unroll 8
        for (int kk = 512; kk < 1024; kk += 32)
            a1 = MFMA16(*(const short8*)(f0 + kk), *(const short8*)(wip + kk), a1);
        g_wait(ctr, ep * 64u);             // h(t) visible (trivial at t=0)
        stageN(hbuf(t) + ((size_t)(bg * 16) << 10), hs);
        __syncthreads();
        #pragma unroll 8
        for (int kk = 0; kk < 512; kk += 32)
            a0 = MFMA16(*(const short8*)(f1 + kk), *(const short8*)(whp + kk), a0);
        #pragma unroll 8
        for (int kk = 512; kk < 1024; kk += 32)
            a1 = MFMA16(*(const short8*)(f1 + kk), *(const short8*)(whp + kk), a1);
        gwrite(a0 + a1);
        __syncthreads();
        pointwise(hbuf(t + 1), false);
        g_arrive(ctr); ep++;               // publish h(t+1)
    }

    // ================= out0 projection =================
    g_wait(ctr, ep * 64u);                 // h(SEQ) visible
    proj_step(hbuf(SEQ), Ybase);           // y(0); hs <- h(SEQ) persists
    g_arrive(ctr); ep++;

    // ================= decode: 31 steps, 2 barriers each =================
    for (int d = 1; d < TOUT; d++) {
        // ---- cell(d): h-GEMM first (hs already staged), then wait for y ----
        f32x4 a0 = {0.f,0.f,0.f,0.f}, a1 = {0.f,0.f,0.f,0.f};
        #pragma unroll 8
        for (int kk = 0; kk < 512; kk += 32)
            a0 = MFMA16(*(const short8*)(f1 + kk), *(const short8*)(whp + kk), a0);
        #pragma unroll 8
        for (int kk = 512; kk < 1024; kk += 32)
            a1 = MFMA16(*(const short8*)(f1 + kk), *(const short8*)(whp + kk), a1);
        g_wait(ctr, ep * 64u);             // y(d-1) visible
        softlse(Ybase + (size_t)(d - 1) * NE, out + (size_t)(d - 1) * NE, true);
        __syncthreads();                   // xs ready
        #pragma unroll 8
        for (int kk = 0; kk < 512; kk += 32)
            a0 = MFMA16(*(const short8*)(f0 + kk), *(const short8*)(wip + kk), a0);
        #pragma unroll 8
        for (int kk = 512; kk < 1024; kk += 32)
            a1 = MFMA16(*(const short8*)(f0 + kk), *(const short8*)(wip + kk), a1);
        gwrite(a0 + a1);
        __syncthreads();
        pointwise(hbuf(SEQ + d), d == TOUT - 1);
        g_arrive(ctr); ep++;               // publish h(SEQ+d)

        // ---- proj(d) ----
        g_wait(ctr, ep * 64u);             // h(SEQ+d) visible
        proj_step(hbuf(SEQ + d), Ybase + (size_t)d * NE);
        g_arrive(ctr); ep++;               // publish y(d)
    }

    // ================= epilogue: out[31] = y(31) - lse =================
    g_wait(ctr, ep * 64u);                 // y(31) visible
    softlse(Ybase + (size_t)(TOUT - 1) * NE, out + (size_t)(TOUT - 1) * NE, false);
}

// ---------------------------------------------------------------------------
extern "C" void kernel_launch(void* const* d_in, const int* in_sizes, int n_in,
                              void* d_out, int out_size, void* d_ws, size_t ws_size,
                              hipStream_t stream)
{
    const float* input = (const float*)d_in[0];   // [128,64,1024]
    const float* h0    = (const float*)d_in[1];
    const float* c0    = (const float*)d_in[2];
    const float* W_ih  = (const float*)d_in[3];   // [4096,1024]
    const float* W_hh  = (const float*)d_in[4];
    const float* b_ih  = (const float*)d_in[5];
    const float* b_hh  = (const float*)d_in[6];
    const float* W_out = (const float*)d_in[7];   // [1024,1024]
    const float* b_out = (const float*)d_in[8];
    float* out = (float*)d_out;                   // [32,64,1024] + h + c

    char* w = (char*)d_ws;                                    // bytes
    ushort*    Whh_bf = (ushort*)   (w + 0);                  //  8,388,608
    ushort*    Wih_bf = (ushort*)   (w + 8388608);            //  8,388,608
    ushort*    Wout_bf= (ushort*)   (w + 16777216);           //  2,097,152
    ushort*    Xbf    = (ushort*)   (w + 18874368);           // 16,777,216
    ushort*    Hbase  = (ushort*)   (w + 35651584);           // 20,971,520
    float*     Ybase  = (float*)    (w + 56623104);           //  8,388,608
    unsigned*  bar    = (unsigned*) (w + 65011712);           //      4,096
    // total ~65.0 MB (proven budget: 86.7 MB)

    cvt_bf16<<<dim3(4096), dim3(256), 0, stream>>>(W_ih,  Wih_bf,  NG * HD);
    cvt_bf16<<<dim3(4096), dim3(256), 0, stream>>>(W_hh,  Whh_bf,  NG * HD);
    cvt_bf16<<<dim3(1024), dim3(256), 0, stream>>>(W_out, Wout_bf, HD * HD);
    cvt_bf16<<<dim3(8192), dim3(256), 0, stream>>>(input, Xbf, SEQ * NE);
    prep<<<dim3(256), dim3(256), 0, stream>>>(
        h0, Hbase + (size_t)(NHBUF - 1) * NE, bar);

    const ushort* a0 = Wih_bf;  const ushort* a1 = Whh_bf;
    const ushort* a2 = Wout_bf; const ushort* a3 = Xbf;
    ushort* a4 = Hbase; float* a5 = Ybase; unsigned* a6 = bar;
    const float* a7 = b_ih; const float* a8 = b_hh; const float* a9 = b_out;
    const float* a10 = c0; float* a11 = out;
    void* args[] = {&a0, &a1, &a2, &a3, &a4, &a5, &a6, &a7, &a8, &a9, &a10, &a11};
    hipLaunchCooperativeKernel((const void*)lstm_coop, dim3(256), dim3(256),
                               args, 0, stream);
}

// Round 2
// 1878.169 us; speedup vs baseline: 1.0744x; 1.0744x over previous
//
#include <hip/hip_runtime.h>
#include <math.h>

// Problem dims (fixed by reference)
#define SEQ    128
#define BATCH  64
#define HD     1024
#define NG     4096
#define TOUT   32
#define NE     65536      // BATCH*HD
#define CHS    32         // encode steps per chunk
#define MCH    2048       // rows per gemm chunk = CHS*BATCH
#define NHBUF  160        // SEQ + TOUT h buffers (write-once rotation)
#define NBAR   1024       // barrier words (4 counters, 256B apart)

typedef __attribute__((ext_vector_type(8))) short    short8;
typedef __attribute__((ext_vector_type(4))) float    f32x4;
typedef __attribute__((ext_vector_type(4))) _Float16 f16x4;

#define MFMA16(a,b,c) __builtin_amdgcn_mfma_f32_16x16x32_bf16((a),(b),(c),0,0,0)

__device__ __forceinline__ ushort bf16_rne(float x) {
    union { float f; unsigned u; } v; v.f = x;
    unsigned r = v.u + 0x7FFF + ((v.u >> 16) & 1);
    return (ushort)(r >> 16);
}

// device-coherent (agent-scope) store: push to coherence point, no fences
__device__ __forceinline__ void cstore32(void* p, unsigned v) {
    __hip_atomic_store((unsigned*)p, v, __ATOMIC_RELAXED, __HIP_MEMORY_SCOPE_AGENT);
}

// ---------------------------------------------------------------------------
// fp32 -> bf16 (RNE), 4 elems/thread; n % 1024 == 0
// ---------------------------------------------------------------------------
__global__ __launch_bounds__(256) void cvt_bf16(
    const float* __restrict__ src, ushort* __restrict__ dst, int n)
{
    int i = (blockIdx.x * 256 + threadIdx.x) * 4;
    if (i < n) {
        float4 v = *(const float4*)(src + i);
        ushort4 o;
        o.x = bf16_rne(v.x); o.y = bf16_rne(v.y);
        o.z = bf16_rne(v.z); o.w = bf16_rne(v.w);
        *(ushort4*)(dst + i) = o;
    }
}

// prep: h0 -> bf16 into hbuf(0); cbuf = c0; zero barrier counters.
__global__ __launch_bounds__(256) void prep(
    const float* __restrict__ h0, const float* __restrict__ c0,
    ushort* __restrict__ h0b, float* __restrict__ cbuf, unsigned* __restrict__ bar)
{
    int i = blockIdx.x * 256 + threadIdx.x;
    h0b[i] = bf16_rne(h0[i]);
    cbuf[i] = c0[i];
    if (blockIdx.x == 0)
        for (int k = threadIdx.x; k < NBAR; k += 256) bar[k] = 0u;
}

// ---------------------------------------------------------------------------
// Chunk GEMM: XgT[gcol][m] = sum_k A[m][k]*Wih[gcol][k], A bf16 [2048][1024],
// out fp16 transposed (m-pitch 2048). grid (4096/128, 2048/128) = (32,16).
// ---------------------------------------------------------------------------
__global__ __launch_bounds__(256) void gemm_xgt(
    const ushort* __restrict__ A, const ushort* __restrict__ Wih,
    _Float16* __restrict__ XgT)
{
    const int wave = threadIdx.x >> 6, lane = threadIdx.x & 63;
    const int l15 = lane & 15, q8 = (lane >> 4) * 8, r0 = (lane >> 4) * 4;
    const int wr = wave >> 1, wc = wave & 1;
    const int m0 = blockIdx.y * 128 + wr * 64;
    const int n0 = blockIdx.x * 128 + wc * 64;

    const ushort* ap[4];
    const ushort* bp[4];
    #pragma unroll
    for (int f = 0; f < 4; f++) {
        ap[f] = A   + (size_t)(m0 + f * 16 + l15) * 1024 + q8;
        bp[f] = Wih + (size_t)(n0 + f * 16 + l15) * 1024 + q8;
    }

    f32x4 acc[4][4];
    #pragma unroll
    for (int f = 0; f < 4; f++)
        #pragma unroll
        for (int g = 0; g < 4; g++)
            acc[f][g] = (f32x4){0.f, 0.f, 0.f, 0.f};

    for (int kk = 0; kk < 1024; kk += 32) {
        short8 a[4], b[4];
        #pragma unroll
        for (int f = 0; f < 4; f++) {
            a[f] = *(const short8*)(ap[f] + kk);
            b[f] = *(const short8*)(bp[f] + kk);
        }
        #pragma unroll
        for (int f = 0; f < 4; f++)
            #pragma unroll
            for (int g = 0; g < 4; g++)
                acc[f][g] = MFMA16(a[f], b[g], acc[f][g]);
    }

    #pragma unroll
    for (int f = 0; f < 4; f++) {
        const int mbase = m0 + f * 16 + r0;
        #pragma unroll
        for (int g = 0; g < 4; g++) {
            const int gcol = n0 + g * 16 + l15;
            *(f16x4*)(XgT + (size_t)gcol * MCH + mbase) =
                __builtin_convertvector(acc[f][g], f16x4);
        }
    }
}

// ---------------------------------------------------------------------------
// Flat monotonic group barrier (64 blocks/group).
// arrive: drain stores, block-sync, one fetch_add on the group counter.
// wait:   thread 0 polls counter >= 64*target (monotonic across all launches
//         of one kernel_launch; prep zeroes it once per invocation).
// Post-last-arrival chain: ~1 atomic flight + poll detect (~1.5 L3 RTs)
// vs the old sub->root->release->poll tree (~4 RTs).
// ---------------------------------------------------------------------------
__device__ __forceinline__ void g_arrive(unsigned* ctr) {
    asm volatile("s_waitcnt vmcnt(0) lgkmcnt(0)" ::: "memory");
    __syncthreads();
    if (threadIdx.x == 0)
        __hip_atomic_fetch_add(ctr, 1u, __ATOMIC_RELAXED, __HIP_MEMORY_SCOPE_AGENT);
}
__device__ __forceinline__ void g_wait(unsigned* ctr, unsigned tgt) {
    if (threadIdx.x == 0) {
        while (__hip_atomic_load(ctr, __ATOMIC_RELAXED, __HIP_MEMORY_SCOPE_AGENT) < tgt)
            __builtin_amdgcn_s_sleep(1);
    }
    __syncthreads();
}

// ---------------------------------------------------------------------------
// Stage 16x1024 bf16 tile via NORMAL cached loads (write-once buffers make
// this safe); 8 loads batched in regs then 8 LDS stores (pitch 1032).
// ---------------------------------------------------------------------------
__device__ __forceinline__ void stageN(const ushort* __restrict__ src,
                                       ushort* __restrict__ dst)
{
    const int tid = threadIdx.x;
    short8 t[8];
    #pragma unroll
    for (int i = 0; i < 8; i++) {
        int idx = i * 256 + tid;
        t[i] = *(const short8*)(src + ((size_t)(idx >> 7) << 10) + (idx & 127) * 8);
    }
    #pragma unroll
    for (int i = 0; i < 8; i++) {
        int idx = i * 256 + tid;
        *(short8*)&dst[(idx >> 7) * 1032 + (idx & 127) * 8] = t[i];
    }
}

// ---------------------------------------------------------------------------
// Persistent cooperative LSTM segment. Block (bg=blk>>6, ug=blk&63):
// cell = 16-batch x 16-unit tile (wave = gate type); proj = 16x16 y patch
// (wave split-K). Log-softmax is folded into the next cell: every block
// redundantly computes lse for its 16 rows (spill-free via LDS scratch ys)
// and builds xs = bf16(y - lse) directly -> uniform control flow, decode is
// 2 barriers/step (was 3 + serial softmax phase), xd buffer gone.
// The 4 bg groups are fully independent -> per-group flat counters.
// h buffers rotate (write-once) in REVERSE address order; y has a 32-slot
// write-once rotation so normal cached loads of it are stale-safe.
// ---------------------------------------------------------------------------
__global__ __launch_bounds__(256, 1) void lstm_coop(
    const ushort* __restrict__ Wih, const ushort* __restrict__ Whh,
    const ushort* __restrict__ Wout, const _Float16* __restrict__ XgT,
    ushort* __restrict__ Hbase, float* __restrict__ Ybase,
    unsigned* __restrict__ bar,
    const float* __restrict__ b_ih, const float* __restrict__ b_hh,
    const float* __restrict__ b_out, float* __restrict__ cbuf,
    float* __restrict__ out, int t0, int nsteps, int dodec, unsigned ep0)
{
    __shared__ ushort xs[16 * 1032];   // x tile (encode: unused; decode: bf16(y-lse))
    __shared__ ushort hs[16 * 1032];   // h tile (persists proj -> next cell)
    __shared__ float  ys[16 * 1028];   // per-thread f32 y scratch (no VGPR spill)
    __shared__ float  gbuf[1088];

    const int blk  = blockIdx.x;
    const int bg   = blk >> 6, ug = blk & 63;
    const int tid  = threadIdx.x;
    const int wave = tid >> 6, lane = tid & 63;
    const int l15  = lane & 15, q8 = (lane >> 4) * 8, r0 = (lane >> 4) * 4;
    const int b    = tid >> 4, u = tid & 15;

    unsigned* ctr = bar + bg * 64;     // 256B apart per group
    unsigned ep = ep0;                 // arrivals so far (monotonic)

    const int gi = ug * 16 + u;
    const float bs0 = b_ih[gi]        + b_hh[gi];
    const float bs1 = b_ih[1024 + gi] + b_hh[1024 + gi];
    const float bs2 = b_ih[2048 + gi] + b_hh[2048 + gi];
    const float bs3 = b_ih[3072 + gi] + b_hh[3072 + gi];
    const int cidx = ((bg * 16 + b) << 10) + gi;
    float c_reg = cbuf[cidx];

    const ushort* wip = Wih + (((size_t)(wave * 1024 + ug * 16 + l15)) << 10) + q8;
    const ushort* whp = Whh + (((size_t)(wave * 1024 + ug * 16 + l15)) << 10) + q8;
    const ushort* wop = Wout + (((size_t)(ug * 16 + l15)) << 10) + wave * 256 + q8;
    const _Float16* xgp = XgT + (size_t)(wave * 1024 + ug * 16 + l15) * MCH
                              + bg * 16 + r0;
    const ushort* f0 = xs + l15 * 1032 + q8;
    const ushort* f1 = hs + l15 * 1032 + q8;

    auto hbuf = [&](int t) -> ushort* {
        return Hbase + (size_t)(NHBUF - 1 - t) * NE;
    };

    auto gwrite = [&](f32x4 acc) {
        #pragma unroll
        for (int r = 0; r < 4; r++)
            gbuf[(r0 + r) * 68 + wave * 16 + l15] = acc[r];
    };

    auto pointwise = [&](ushort* hnxt, bool fin) {
        float ig = gbuf[b * 68 + u]      + bs0;
        float fg = gbuf[b * 68 + 16 + u] + bs1;
        float gg = gbuf[b * 68 + 32 + u] + bs2;
        float og = gbuf[b * 68 + 48 + u] + bs3;
        float si = 1.f / (1.f + expf(-ig));
        float sf = 1.f / (1.f + expf(-fg));
        float so = 1.f / (1.f + expf(-og));
        float tg = tanhf(gg);
        float cn = sf * c_reg + si * tg;
        c_reg = cn;
        float hn = so * tanhf(cn);
        ushort hb16 = bf16_rne(hn);
        unsigned hi = (unsigned)(ushort)__shfl_down((int)hb16, 1);
        if ((u & 1) == 0)
            cstore32((void*)(hnxt + cidx), (unsigned)hb16 | (hi << 16));
        if (fin) {
            out[(size_t)TOUT * NE + cidx]       = hn;
            out[(size_t)(TOUT + 1) * NE + cidx] = cn;
        }
    };

    auto proj_step = [&](const ushort* hcur, float* ydst) {
        stageN(hcur + ((size_t)(bg * 16) << 10), hs);
        __syncthreads();
        const ushort* hpp = hs + l15 * 1032 + wave * 256 + q8;
        f32x4 ac = {0.f, 0.f, 0.f, 0.f};
        #pragma unroll
        for (int kk = 0; kk < 256; kk += 32)
            ac = MFMA16(*(const short8*)(hpp + kk), *(const short8*)(wop + kk), ac);
        #pragma unroll
        for (int r = 0; r < 4; r++)
            gbuf[wave * 256 + (r0 + r) * 16 + l15] = ac[r];
        __syncthreads();
        float vv = gbuf[b * 16 + u] + gbuf[256 + b * 16 + u]
                 + gbuf[512 + b * 16 + u] + gbuf[768 + b * 16 + u]
                 + b_out[ug * 16 + u];
        union { float f; unsigned uu; } cv; cv.f = vv;
        cstore32(ydst + (size_t)(bg * 16 + b) * 1024 + ug * 16 + u, cv.uu);
    };

    // Distributed, spill-free log-softmax: thread (b,u) owns row bg*16+b,
    // cols {u*4 + s*64}. Values stream global -> LDS scratch (ys), reductions
    // are 16-lane shfl trees; out patch + xs fill re-read from ys.
    auto softlse = [&](const float* yb, float* outp, bool fill_xs) {
        const float* yrow = yb + (size_t)(bg * 16 + b) * 1024 + u * 4;
        float* yscr = ys + b * 1028 + u * 4;
        float mx = -3.4e38f;
        #pragma unroll
        for (int s = 0; s < 16; s++) {
            float4 v = *(const float4*)(yrow + s * 64);
            *(float4*)(yscr + s * 64) = v;
            mx = fmaxf(mx, fmaxf(fmaxf(v.x, v.y), fmaxf(v.z, v.w)));
        }
        #pragma unroll
        for (int k = 1; k < 16; k <<= 1)
            mx = fmaxf(mx, __shfl_xor(mx, k, 16));
        float sm = 0.f;
        #pragma unroll
        for (int s = 0; s < 16; s++) {
            float4 v = *(const float4*)(yscr + s * 64);
            sm += expf(v.x - mx) + expf(v.y - mx)
                + expf(v.z - mx) + expf(v.w - mx);
        }
        #pragma unroll
        for (int k = 1; k < 16; k <<= 1)
            sm += __shfl_xor(sm, k, 16);
        const float lse = mx + logf(sm);
        if ((u >> 2) == (ug & 3)) {        // these lanes hold cols ug*16..+15
            float4 v = *(const float4*)(yscr + (ug >> 2) * 64);
            v.x -= lse; v.y -= lse; v.z -= lse; v.w -= lse;
            *(float4*)(outp + (size_t)(bg * 16 + b) * 1024 + ug * 16 + (u & 3) * 4) = v;
        }
        if (fill_xs) {
            ushort* xrow = &xs[b * 1032 + u * 4];
            #pragma unroll
            for (int s = 0; s < 16; s++) {
                float4 v = *(const float4*)(yscr + s * 64);
                ushort4 w4;
                w4.x = bf16_rne(v.x - lse); w4.y = bf16_rne(v.y - lse);
                w4.z = bf16_rne(v.z - lse); w4.w = bf16_rne(v.w - lse);
                *(ushort4*)(xrow + s * 64) = w4;
            }
        }
    };

    // ================= encode segment: 1 barrier/step =================
    for (int s = 0; s < nsteps; s++) {
        const int t = t0 + s;
        f16x4 xg4 = *(const f16x4*)(xgp + (size_t)s * 64);   // indep of h(t)
        g_wait(ctr, ep * 64u);             // h(t) visible
        stageN(hbuf(t) + ((size_t)(bg * 16) << 10), hs);
        __syncthreads();
        f32x4 a0 = __builtin_convertvector(xg4, f32x4);
        f32x4 a1 = {0.f, 0.f, 0.f, 0.f};
        #pragma unroll 8
        for (int kk = 0; kk < 512; kk += 32)
            a0 = MFMA16(*(const short8*)(f1 + kk), *(const short8*)(whp + kk), a0);
        #pragma unroll 8
        for (int kk = 512; kk < 1024; kk += 32)
            a1 = MFMA16(*(const short8*)(f1 + kk), *(const short8*)(whp + kk), a1);
        gwrite(a0 + a1);
        __syncthreads();
        pointwise(hbuf(t + 1), false);
        g_arrive(ctr); ep++;               // publish h(t+1)
    }

    if (!dodec) {
        cbuf[cidx] = c_reg;   // spill recurrent c for the next segment
        return;
    }

    // ================= out0 =================
    g_wait(ctr, ep * 64u);                 // h(SEQ) visible
    proj_step(hbuf(SEQ), Ybase);           // y slot 0; hs <- h(SEQ) persists
    g_arrive(ctr); ep++;

    // ================= decode: 31 steps, 2 barriers each =================
    for (int d = 1; d < TOUT; d++) {
        // ---- cell(d): h-GEMM in the y-wait shadow (hs staged by proj) ----
        f32x4 a0 = {0.f,0.f,0.f,0.f}, a1 = {0.f,0.f,0.f,0.f};
        #pragma unroll 8
        for (int kk = 0; kk < 512; kk += 32)
            a0 = MFMA16(*(const short8*)(f1 + kk), *(const short8*)(whp + kk), a0);
        #pragma unroll 8
        for (int kk = 512; kk < 1024; kk += 32)
            a1 = MFMA16(*(const short8*)(f1 + kk), *(const short8*)(whp + kk), a1);
        g_wait(ctr, ep * 64u);             // y(d-1) visible
        softlse(Ybase + (size_t)(d - 1) * NE, out + (size_t)(d - 1) * NE, true);
        __syncthreads();                   // xs ready
        #pragma unroll 8
        for (int kk = 0; kk < 512; kk += 32)
            a0 = MFMA16(*(const short8*)(f0 + kk), *(const short8*)(wip + kk), a0);
        #pragma unroll 8
        for (int kk = 512; kk < 1024; kk += 32)
            a1 = MFMA16(*(const short8*)(f0 + kk), *(const short8*)(wip + kk), a1);
        gwrite(a0 + a1);
        __syncthreads();
        pointwise(hbuf(SEQ + d), d == TOUT - 1);
        g_arrive(ctr); ep++;               // publish h(SEQ+d)

        // ---- proj(d) ----
        g_wait(ctr, ep * 64u);             // h(SEQ+d) visible
        proj_step(hbuf(SEQ + d), Ybase + (size_t)d * NE);
        g_arrive(ctr); ep++;               // publish y(d)
    }

    // ================= epilogue: out[31] = y(31) - lse =================
    g_wait(ctr, ep * 64u);                 // y(31) visible
    softlse(Ybase + (size_t)(TOUT - 1) * NE, out + (size_t)(TOUT - 1) * NE, false);
}

// ---------------------------------------------------------------------------
extern "C" void kernel_launch(void* const* d_in, const int* in_sizes, int n_in,
                              void* d_out, int out_size, void* d_ws, size_t ws_size,
                              hipStream_t stream)
{
    const float* input = (const float*)d_in[0];   // [128,64,1024]
    const float* h0    = (const float*)d_in[1];
    const float* c0    = (const float*)d_in[2];
    const float* W_ih  = (const float*)d_in[3];   // [4096,1024]
    const float* W_hh  = (const float*)d_in[4];
    const float* b_ih  = (const float*)d_in[5];
    const float* b_hh  = (const float*)d_in[6];
    const float* W_out = (const float*)d_in[7];   // [1024,1024]
    const float* b_out = (const float*)d_in[8];
    float* out = (float*)d_out;                   // [32,64,1024] + h + c

    char* w = (char*)d_ws;                                    // bytes
    ushort*    Whh_bf = (ushort*)   (w + 0);                  //  8,388,608
    ushort*    Wih_bf = (ushort*)   (w + 8388608);            //  8,388,608
    ushort*    Wout_bf= (ushort*)   (w + 16777216);           //  2,097,152
    _Float16*  XgT    = (_Float16*) (w + 18874368);           // 16,777,216
    ushort*    Xbc    = (ushort*)   (w + 35651584);           //  4,194,304
    ushort*    Hbase  = (ushort*)   (w + 39845888);           // 20,971,520
    float*     Ybase  = (float*)    (w + 60817408);           //  8,388,608 (32 slots)
    float*     cbuf   = (float*)    (w + 69206016);           //    262,144
    unsigned*  bar    = (unsigned*) (w + 69468160);           //      4,096
    // total ~69.5 MB (proven budget: 86.7 MB)

    cvt_bf16<<<dim3(4096), dim3(256), 0, stream>>>(W_ih,  Wih_bf,  NG * HD);
    cvt_bf16<<<dim3(4096), dim3(256), 0, stream>>>(W_hh,  Whh_bf,  NG * HD);
    cvt_bf16<<<dim3(1024), dim3(256), 0, stream>>>(W_out, Wout_bf, HD * HD);
    // hbuf(0) = Hbase + (NHBUF-1)*NE
    prep<<<dim3(256), dim3(256), 0, stream>>>(
        h0, c0, Hbase + (size_t)(NHBUF - 1) * NE, cbuf, bar);

    for (int ch = 0; ch < SEQ / CHS; ch++) {
        cvt_bf16<<<dim3(2048), dim3(256), 0, stream>>>(
            input + (size_t)ch * CHS * NE, Xbc, CHS * NE);
        gemm_xgt<<<dim3(32, 16), dim3(256), 0, stream>>>(Xbc, Wih_bf, XgT);

        const ushort* a0 = Wih_bf;  const ushort* a1 = Whh_bf;
        const ushort* a2 = Wout_bf; const _Float16* a3 = XgT;
        ushort* a4 = Hbase; float* a5 = Ybase; unsigned* a6 = bar;
        const float* a7 = b_ih; const float* a8 = b_hh; const float* a9 = b_out;
        float* a10 = cbuf; float* a11 = out;
        int t0 = ch * CHS, ns = CHS, dodec = (ch == SEQ / CHS - 1) ? 1 : 0;
        unsigned ep0 = (unsigned)(ch * CHS);   // arrivals in prior chunks
        void* args[] = {&a0, &a1, &a2, &a3, &a4, &a5, &a6, &a7,
                        &a8, &a9, &a10, &a11, &t0, &ns, &dodec, &ep0};
        hipLaunchCooperativeKernel((const void*)lstm_coop, dim3(256), dim3(256),
                                   args, 0, stream);
    }
}